// Round 2
// baseline (574.183 us; speedup 1.0000x reference)
//
#include <hip/hip_runtime.h>
#include <math.h>

// Fully fused SNN forward (linearity collapse verified R1-R3, absmax 4.8e-7).
// R6: kill the SMEM drain. R5 post-mortem: occupancy 19->35% moved VALUBusy
// only 59->62% and busy time was identical (156us) -> stall is structural:
// inner loop mixed ds_read (X) with s_load (W). SMEM returns OUT OF ORDER,
// forcing lgkmcnt(0) full drains every k-step that counted waits can't
// pipeline; co-resident waves phase-lock on the same Wt K$-miss stream
// (~300cy drain + 400cy serialized VALU = observed 765 cyc/k).
// Change: stage the W-tile in LDS too; inner loop is pure ds_read + VALU.
// LDS is IN-ORDER -> compiler emits counted lgkmcnt(N) and pipelines the
// unroll-4. W reads are wave-uniform -> HW broadcast, conflict-free.
// Geometry back to 2 batches/block (512 blocks, 4 rows/lane): 200 VALU-cyc
// per wave per k vs 8 LDS reads -> LDS pipe ~65% of VALU budget, not binding.

#define NSTEPS 100
#define NHID 100
#define KDIM 784
#define BKT 16        // 784 = 49 * 16 exact
#define NOUT 10

typedef float v2f __attribute__((ext_vector_type(2)));

// ---- tiny transpose: Wt[k][32*cg + i] = W1[25*cg + i][k], pad i>=25 with 0
__global__ __launch_bounds__(256)
void wt_transpose(const float* __restrict__ W1, float* __restrict__ Wt) {
  const int idx = blockIdx.x * 256 + threadIdx.x;   // 784*128 entries
  if (idx >= KDIM * 128) return;
  const int k = idx >> 7, s = idx & 127, cg = s >> 5, i = s & 31;
  const int j = 25 * cg + i;
  Wt[idx] = (i < 25) ? W1[(size_t)j * KDIM + k] : 0.0f;
}

__global__ __launch_bounds__(256, 2)
void snn_fused5(const float* __restrict__ X, const float* __restrict__ Wt,
                const float* __restrict__ wsyn1p, const float* __restrict__ b1,
                const float* __restrict__ wsyn2p, const float* __restrict__ W2,
                const float* __restrict__ b2, float* __restrict__ out) {
  __shared__ float Xs[BKT][256];     // 16.0 KB: k-major X tile (2 batches)
  __shared__ float Ws[BKT][128];     // 8.0 KB: W tile, row = Wt row copy
  __shared__ float Cs[2][25][106];   // 21.2 KB scan chunk, stride 106
  __shared__ float zsh[2][NHID];

  const int tid = threadIdx.x;
  const int l   = tid & 63;
  const int cg  = __builtin_amdgcn_readfirstlane(tid >> 6);  // wave col group
  const long b0 = 2L * blockIdx.x;

  // X staging identity: thread stages U-row `tid` (t>=100 clamped, discarded)
  const int sb = tid >> 7;
  const int st = ((tid & 127) < NSTEPS) ? (tid & 127) : (NSTEPS - 1);
  const float* __restrict__ Xrow = X + ((b0 + sb) * NSTEPS + st) * (size_t)KDIM;

  // W staging identity: thread stages 8 floats of row (kt + tid>>4)
  const int wkr = tid >> 4;          // 0..15
  const int wcc = 8 * (tid & 15);    // 0..120
  const float* __restrict__ Wg = Wt + (size_t)wkr * 128 + wcc;

  v2f  acc2[4][12];                  // rows 4l..4l+3, col pairs 0..23
  float accs[4];                     // col 24
#pragma unroll
  for (int i = 0; i < 4; ++i) {
    accs[i] = 0.0f;
#pragma unroll
    for (int c = 0; c < 12; ++c) acc2[i][c] = (v2f){0.0f, 0.0f};
  }

  float4 pf[4];                      // prefetched 16-float X row segment
#pragma unroll
  for (int q = 0; q < 4; ++q) pf[q] = *(const float4*)(Xrow + 4 * q);
  float4 wpf0 = *(const float4*)(Wg);
  float4 wpf1 = *(const float4*)(Wg + 4);

  for (int kt = 0; kt < KDIM; kt += BKT) {
    __syncthreads();                 // previous tile's LDS reads complete
#pragma unroll
    for (int q = 0; q < 4; ++q) {
      Xs[4 * q + 0][tid] = pf[q].x;
      Xs[4 * q + 1][tid] = pf[q].y;
      Xs[4 * q + 2][tid] = pf[q].z;
      Xs[4 * q + 3][tid] = pf[q].w;
    }
    *(float4*)&Ws[wkr][wcc]     = wpf0;
    *(float4*)&Ws[wkr][wcc + 4] = wpf1;
    __syncthreads();
    if (kt + BKT < KDIM) {
      const float* xp = Xrow + kt + BKT;
#pragma unroll
      for (int q = 0; q < 4; ++q) pf[q] = *(const float4*)(xp + 4 * q);
      const float* wp = Wg + (size_t)(kt + BKT) * 128;
      wpf0 = *(const float4*)(wp);
      wpf1 = *(const float4*)(wp + 4);
    }

#pragma unroll 4
    for (int k = 0; k < BKT; ++k) {
      const float4 xv = *(const float4*)&Xs[k][4 * l];
      const float* __restrict__ wk = &Ws[k][32 * cg];  // uniform -> broadcast
      float w[26];
#pragma unroll
      for (int i4 = 0; i4 < 6; ++i4)
        *(float4*)(w + 4 * i4) = *(const float4*)(wk + 4 * i4);  // ds_read_b128
      *(v2f*)(w + 24) = *(const v2f*)(wk + 24);                  // ds_read_b64

      const v2f xd0 = {xv.x, xv.x};
      const v2f xd1 = {xv.y, xv.y};
      const v2f xd2 = {xv.z, xv.z};
      const v2f xd3 = {xv.w, xv.w};
#pragma unroll
      for (int c2 = 0; c2 < 12; ++c2) {
        const v2f wv = *(const v2f*)(w + 2 * c2);
        acc2[0][c2] = __builtin_elementwise_fma(xd0, wv, acc2[0][c2]);
        acc2[1][c2] = __builtin_elementwise_fma(xd1, wv, acc2[1][c2]);
        acc2[2][c2] = __builtin_elementwise_fma(xd2, wv, acc2[2][c2]);
        acc2[3][c2] = __builtin_elementwise_fma(xd3, wv, acc2[3][c2]);
      }
      const float w24 = w[24];
      accs[0] = fmaf(xv.x, w24, accs[0]);
      accs[1] = fmaf(xv.y, w24, accs[1]);
      accs[2] = fmaf(xv.z, w24, accs[2]);
      accs[3] = fmaf(xv.w, w24, accs[3]);
    }
  }

  // ---- fused scan epilogue: 4 chunks of 25 timesteps, 2 batches in parallel
  const float inv1 = 1.f / (1.f + expf(-wsyn1p[0]));
  const float inv2 = 1.f / (1.f + expf(-wsyn2p[0]));
  const int sb2 = tid >> 7;
  const int j   = tid & 127;
  const float bj = (j < NHID) ? b1[j] : 0.f;
  float S = 0.f, v1 = 0.f, s2 = 0.f, z = 0.f;
  float at = 0x1p-100f;              // 2^(t-100)

  for (int q = 0; q < 4; ++q) {
    __syncthreads();                 // previous chunk's reads complete
#pragma unroll
    for (int i = 0; i < 4; ++i) {
      const int r  = 4 * l + i;
      const int bb = r >> 7;
      const int t  = r & 127;
      const int tt = t - 25 * q;
      if (t < NSTEPS && tt >= 0 && tt < 25) {
        float* crow = &Cs[bb][tt][25 * cg];
#pragma unroll
        for (int c2 = 0; c2 < 12; ++c2) {
          crow[2 * c2 + 0] = acc2[i][c2].x;
          crow[2 * c2 + 1] = acc2[i][c2].y;
        }
        crow[24] = accs[i];
      }
    }
    __syncthreads();
    if (j < NHID) {
#pragma unroll
      for (int tt = 0; tt < 25; ++tt) {
        const float u = Cs[sb2][tt][j];
        S = S - S * inv1 + u;             // SynapseFilter 1 (h-space)
        const float h = S + bj;
        v1 = v1 + (h - v1) * 0.5f;        // LIF1, tau=2
        const float sp = (v1 >= 1.0f) ? 1.0f : 0.0f;
        v1 = v1 * (1.0f - sp);            // hard reset
        s2 = s2 - s2 * inv2 + sp;         // SynapseFilter 2
        z  = fmaf(at, s2, z);
        at *= 2.0f;
      }
    }
  }

  if (j < NHID) zsh[sb2][j] = z;
  __syncthreads();

  if (tid < 2 * NOUT) {
    const int bb = tid / NOUT;
    const int jo = tid % NOUT;
    float a = b2[jo];
    const float* __restrict__ wrow = W2 + jo * NHID;
#pragma unroll
    for (int jj = 0; jj < NHID; ++jj) a = fmaf(zsh[bb][jj], wrow[jj], a);
    out[(b0 + bb) * NOUT + jo] = a;
  }
}

extern "C" void kernel_launch(void* const* d_in, const int* in_sizes, int n_in,
                              void* d_out, int out_size, void* d_ws, size_t ws_size,
                              hipStream_t stream) {
  const float* x     = (const float*)d_in[0];
  const float* wsyn1 = (const float*)d_in[1];
  const float* W1    = (const float*)d_in[2];
  const float* b1    = (const float*)d_in[3];
  const float* wsyn2 = (const float*)d_in[4];
  const float* W2    = (const float*)d_in[5];
  const float* b2    = (const float*)d_in[6];
  float* out = (float*)d_out;
  float* Wt  = (float*)d_ws;   // 784 x 128 fp32 = 401 KB

  wt_transpose<<<dim3((KDIM * 128 + 255) / 256), dim3(256), 0, stream>>>(W1, Wt);
  snn_fused5<<<dim3(512), dim3(256), 0, stream>>>(x, Wt, wsyn1, b1, wsyn2, W2,
                                                  b2, out);
}